// Round 7
// baseline (1813.309 us; speedup 1.0000x reference)
//
#include <hip/hip_runtime.h>
#include <math.h>

#define Bsz  64
#define Cch  2048
#define Kdim 768
#define Ssp  361
#define CPB  16                      // channels per block (sims staging)
#define REGF (CPB * Ssp)             // 5776 floats = 23104 B per block slice
#define NFULL 22                     // 22 full 1KB DMA issues ...
#define NTAIL 36                     // ... + 1 tail issue with 36 active lanes
#define NCG   (Cch / CPB)            // 128 channel groups

// ---------------------------------------------------------------------------
// Async global->LDS DMA, 16 B per lane per issue. DMA consumes no VGPRs, so
// the compiler cannot sink/serialize it. LDS dest: wave-uniform base + lane*16.
// ---------------------------------------------------------------------------
__device__ __forceinline__ void dma16(const float* g, float* l) {
    __builtin_amdgcn_global_load_lds(
        (const __attribute__((address_space(1))) void*)(g),
        (__attribute__((address_space(3))) void*)(l),
        16, 0, 0);
}

// ---------------------------------------------------------------------------
// K2'': fused qgemm + sims + (last-block) softmax. grid (cg=128, b=64) x 384.
// - Grid transposed (round 6): XCD = cg%8 -> W slices L2-resident (+9.4 us).
// - q-compute hidden under img DMA (round 5).
// - NEW (round 7): k_wts folded in via last-block-per-batch pattern. Each
//   block releases its sims_part write (__threadfence, agent scope) then
//   atomicAdd's cnt[b]; the 128th block acquires and runs the identical
//   384-thread softmax body inline. Removes one kernel + launch boundary.
//   cnt[] is zeroed each iteration by a hipMemsetAsync graph node.
// ---------------------------------------------------------------------------
__global__ __launch_bounds__(384) void k_sims(
    const float* __restrict__ text, const float* __restrict__ W,
    const float* __restrict__ bias, const float* __restrict__ img,
    float* __restrict__ sims_part, float* __restrict__ wts,
    int* __restrict__ cnt)
{
    const int cg = blockIdx.x;          // fast axis -> XCD = cg % 8
    const int b  = blockIdx.y;
    const int tid = threadIdx.x;
    const int lane = tid & 63;
    const int wv   = tid >> 6;

    __shared__ __align__(16) float lds[REGF];
    __shared__ float qpart[16 * 24];
    __shared__ float qL[CPB];
    __shared__ int   lastflag;

    // 1) issue DMA for the img slice (no drain yet)
    const float* region = img + ((size_t)b * Cch + (size_t)cg * CPB) * Ssp;
    for (int i = wv; i < NFULL + 1; i += 6) {
        if (i < NFULL || lane < NTAIL)
            dma16(region + i * 256 + lane * 4, lds + i * 256);
    }

    // 2) q-compute hidden under the DMA: 384 threads = 16 channels x 24 lanes.
    //    W slice is L2-hot (XCD owns 16 cg-slices = 768 KB).
    {
        const int qc = tid / 24;           // 0..15
        const int qj = tid - qc * 24;      // 0..23
        const float4* wr = (const float4*)(W + (size_t)(cg * CPB + qc) * Kdim);
        const float4* tr = (const float4*)(text + (size_t)b * Kdim);
        float acc = 0.f;
        #pragma unroll
        for (int t = 0; t < 8; t++) {
            const float4 w4 = wr[qj + 24 * t];
            const float4 t4 = tr[qj + 24 * t];
            acc += w4.x * t4.x + w4.y * t4.y + w4.z * t4.z + w4.w * t4.w;
        }
        qpart[qc * 24 + qj] = acc;
    }

    // 3) drain DMA (W/text VGPR loads complete too) + barrier
    asm volatile("s_waitcnt vmcnt(0)" ::: "memory");
    __syncthreads();

    if (tid < CPB) {
        float q = bias[cg * CPB + tid];
        #pragma unroll
        for (int j = 0; j < 24; j++) q += qpart[tid * 24 + j];
        qL[tid] = q;
    }
    __syncthreads();

    // 4) staged dot products: thread s<361 does 16 conflict-free LDS reads
    if (tid < Ssp) {
        float acc = 0.f;
        #pragma unroll
        for (int c = 0; c < CPB; c++)
            acc += qL[c] * lds[c * Ssp + tid];
        sims_part[((size_t)b * NCG + cg) * Ssp + tid] = acc;
    }

    // 5) last-block-per-batch softmax (replaces the k_wts dispatch)
    __threadfence();                      // release sims_part (agent scope)
    if (tid == 0) {
        const int old = atomicAdd(&cnt[b], 1);
        lastflag = (old == NCG - 1);
    }
    __syncthreads();
    if (!lastflag) return;
    __threadfence();                      // acquire all 128 partials

    {
        float* red = qpart;               // reuse shared scratch

        float s0 = -1e30f;
        if (tid < Ssp) {
            const float* sp = sims_part + (size_t)b * NCG * Ssp + tid;
            float a = 0.f;
            for (int g0 = 0; g0 < NCG; g0 += 16) {
                float v[16];
                #pragma unroll
                for (int j = 0; j < 16; j++) v[j] = sp[(size_t)(g0 + j) * Ssp];
                #pragma unroll
                for (int j = 0; j < 16; j++) a += v[j];
            }
            s0 = a;
        }

        float m = s0;
        #pragma unroll
        for (int off = 32; off; off >>= 1) m = fmaxf(m, __shfl_xor(m, off));
        if (lane == 0) red[wv] = m;
        __syncthreads();
        m = red[0];
        #pragma unroll
        for (int w = 1; w < 6; w++) m = fmaxf(m, red[w]);
        __syncthreads();

        const float e0 = (tid < Ssp) ? __expf(s0 - m) : 0.f;
        float l = e0;
        #pragma unroll
        for (int off = 32; off; off >>= 1) l += __shfl_xor(l, off);
        if (lane == 0) red[wv] = l;
        __syncthreads();
        l = red[0] + red[1] + red[2] + red[3] + red[4] + red[5];

        if (tid < Ssp)
            wts[(size_t)b * Ssp + tid] = e0 / l;
    }
}

// ---------------------------------------------------------------------------
// K4: weighted pooling, direct reads. grid (64, 32) = 2048 blocks = 8/CU
// (round-5 occupancy fix). Wave owns 16 channels, 4-row ILP, lane = s.
// Near the mixed HBM/L3 floor (~17 us) — unchanged.
// ---------------------------------------------------------------------------
__global__ __launch_bounds__(256) void k_pool(
    const float* __restrict__ img, const float* __restrict__ wts,
    float* __restrict__ out)
{
    const int b    = blockIdx.x;
    const int cg   = blockIdx.y;          // 32 groups x 64 channels
    const int tid  = threadIdx.x;
    const int lane = tid & 63;
    const int wv   = tid >> 6;

    __shared__ float wL[Ssp];
    for (int s = tid; s < Ssp; s += 256)
        wL[s] = wts[(size_t)b * Ssp + s];
    __syncthreads();

    // preload this lane's 6 weights once (s = lane + 64k), reused for all rows
    float wreg[6];
    #pragma unroll
    for (int k = 0; k < 6; k++) {
        const int s = lane + 64 * k;
        wreg[k] = (s < Ssp) ? wL[s] : 0.f;   // stride-1 lanes: conflict-free
    }

    const float* base = img + ((size_t)b * Cch + (size_t)cg * 64) * Ssp;
    const int c0 = wv * 16;                  // wave's 16 channels

    for (int i = 0; i < 16; i += 4) {
        const float* r0 = base + (size_t)(c0 + i + 0) * Ssp;
        const float* r1 = base + (size_t)(c0 + i + 1) * Ssp;
        const float* r2 = base + (size_t)(c0 + i + 2) * Ssp;
        const float* r3 = base + (size_t)(c0 + i + 3) * Ssp;

        float a0 = 0.f, a1 = 0.f, a2 = 0.f, a3 = 0.f;
        #pragma unroll
        for (int k = 0; k < 6; k++) {
            const int s = lane + 64 * k;
            const bool ok = (s < Ssp);
            const float v0 = ok ? r0[s] : 0.f;
            const float v1 = ok ? r1[s] : 0.f;
            const float v2 = ok ? r2[s] : 0.f;
            const float v3 = ok ? r3[s] : 0.f;
            a0 += v0 * wreg[k];
            a1 += v1 * wreg[k];
            a2 += v2 * wreg[k];
            a3 += v3 * wreg[k];
        }
        #pragma unroll
        for (int off = 32; off; off >>= 1) {
            a0 += __shfl_xor(a0, off);
            a1 += __shfl_xor(a1, off);
            a2 += __shfl_xor(a2, off);
            a3 += __shfl_xor(a3, off);
        }
        if (lane == 0) {
            float* o = out + (size_t)b * Cch + (size_t)cg * 64 + c0 + i;
            o[0] = a0; o[1] = a1; o[2] = a2; o[3] = a3;
        }
    }
}

// ---------------------------------------------------------------------------
extern "C" void kernel_launch(void* const* d_in, const int* in_sizes, int n_in,
                              void* d_out, int out_size, void* d_ws, size_t ws_size,
                              hipStream_t stream) {
    const float* text = (const float*)d_in[0];   // [64, 768]
    const float* img  = (const float*)d_in[1];   // [64, 2048, 19, 19]
    const float* W    = (const float*)d_in[2];   // [2048, 768]
    const float* bias = (const float*)d_in[3];   // [2048]
    float* out = (float*)d_out;                  // [64, 2048]

    // ws: [cnt (64 ints) in the dead qT slot, 512 KB] + sims_part + wts
    int*   cnt       = (int*)d_ws;
    float* sims_part = (float*)d_ws + (size_t)Cch * Bsz;
    float* wts       = sims_part + (size_t)Bsz * NCG * Ssp;

    // Zero the per-batch completion counters (graph-capturable memset node).
    hipMemsetAsync(cnt, 0, Bsz * sizeof(int), stream);

    k_sims <<<dim3(NCG, Bsz), 384, 0, stream>>>(text, W, bias, img,
                                                sims_part, wts, cnt);
    k_pool <<<dim3(Bsz, 32),  256, 0, stream>>>(img, wts, out);
}

// Round 8
// 303.169 us; speedup vs baseline: 5.9812x; 5.9812x over previous
//
#include <hip/hip_runtime.h>
#include <math.h>

#define Bsz  64
#define Cch  2048
#define Kdim 768
#define Ssp  361
#define CPB  16                      // channels per block (sims staging)
#define REGF (CPB * Ssp)             // 5776 floats = 23104 B per block slice
#define NFULL 22                     // 22 full 1KB DMA issues ...
#define NTAIL 36                     // ... + 1 tail issue with 36 active lanes
#define NCG   (Cch / CPB)            // 128 channel groups

// ---------------------------------------------------------------------------
// Async global->LDS DMA, 16 B per lane per issue. DMA consumes no VGPRs, so
// the compiler cannot sink/serialize it. LDS dest: wave-uniform base + lane*16.
// ---------------------------------------------------------------------------
__device__ __forceinline__ void dma16(const float* g, float* l) {
    __builtin_amdgcn_global_load_lds(
        (const __attribute__((address_space(1))) void*)(g),
        (__attribute__((address_space(3))) void*)(l),
        16, 0, 0);
}

// ---------------------------------------------------------------------------
// K2': fused qgemm + sims. grid (cg=128, b=64) x 384.
// - Grid transposed (round 6): XCD = cg%8 -> each XCD owns 16 cg-slices
//   (768 KB of W, L2-RESIDENT; fetched from HBM once, 63 L2 hits). The
//   (b, cg) ordering streamed all 6 MB of W through every 4 MB L2 (~18 us).
// - q-compute hidden under the img DMA (round 5): W/text reads + FMAs
//   complete while the 23 KB slice DMA is in flight.
// - Round-7 NEGATIVE result (do not retry): folding the softmax in via
//   last-block-per-batch + __threadfence cost 1509 us — device-scope fences
//   force per-block L2 writebacks on non-coherent XCD L2s (72 GB/s effective).
// ---------------------------------------------------------------------------
__global__ __launch_bounds__(384) void k_sims(
    const float* __restrict__ text, const float* __restrict__ W,
    const float* __restrict__ bias, const float* __restrict__ img,
    float* __restrict__ sims_part)
{
    const int cg = blockIdx.x;          // fast axis -> XCD = cg % 8
    const int b  = blockIdx.y;
    const int tid = threadIdx.x;
    const int lane = tid & 63;
    const int wv   = tid >> 6;

    __shared__ __align__(16) float lds[REGF];
    __shared__ float qpart[16 * 24];
    __shared__ float qL[CPB];

    // 1) issue DMA for the img slice (no drain yet)
    const float* region = img + ((size_t)b * Cch + (size_t)cg * CPB) * Ssp;
    for (int i = wv; i < NFULL + 1; i += 6) {
        if (i < NFULL || lane < NTAIL)
            dma16(region + i * 256 + lane * 4, lds + i * 256);
    }

    // 2) q-compute hidden under the DMA: 384 threads = 16 channels x 24 lanes.
    //    Thread (qc,qj): partial dot over 8 float4's (192 float4 = 768 floats).
    //    W slice is L2-hot (see header comment).
    {
        const int qc = tid / 24;           // 0..15
        const int qj = tid - qc * 24;      // 0..23
        const float4* wr = (const float4*)(W + (size_t)(cg * CPB + qc) * Kdim);
        const float4* tr = (const float4*)(text + (size_t)b * Kdim);
        float acc = 0.f;
        #pragma unroll
        for (int t = 0; t < 8; t++) {
            const float4 w4 = wr[qj + 24 * t];
            const float4 t4 = tr[qj + 24 * t];
            acc += w4.x * t4.x + w4.y * t4.y + w4.z * t4.z + w4.w * t4.w;
        }
        qpart[qc * 24 + qj] = acc;
    }

    // 3) drain DMA (W/text VGPR loads complete too) + barrier
    asm volatile("s_waitcnt vmcnt(0)" ::: "memory");
    __syncthreads();

    if (tid < CPB) {
        float q = bias[cg * CPB + tid];
        #pragma unroll
        for (int j = 0; j < 24; j++) q += qpart[tid * 24 + j];
        qL[tid] = q;
    }
    __syncthreads();

    // 4) staged dot products: thread s<361 does 16 conflict-free LDS reads
    if (tid < Ssp) {
        float acc = 0.f;
        #pragma unroll
        for (int c = 0; c < CPB; c++)
            acc += qL[c] * lds[c * Ssp + tid];
        sims_part[((size_t)b * NCG + cg) * Ssp + tid] = acc;
    }
}

// ---------------------------------------------------------------------------
// K3: weights. grid = 64 x 384; sums the 128 partials (L2-hot), block
// softmax, writes PRE-NORMALIZED weights. (~1-2 us, at floor.)
// ---------------------------------------------------------------------------
__global__ __launch_bounds__(384) void k_wts(
    const float* __restrict__ sims_part, float* __restrict__ wts)
{
    const int b   = blockIdx.x;
    const int tid = threadIdx.x;
    const int lane = tid & 63;
    const int wv   = tid >> 6;

    __shared__ float red[6];

    float s0 = -1e30f;
    if (tid < Ssp) {
        const float* sp = sims_part + (size_t)b * NCG * Ssp + tid;
        float a = 0.f;
        for (int g0 = 0; g0 < 128; g0 += 16) {
            float v[16];
            #pragma unroll
            for (int j = 0; j < 16; j++) v[j] = sp[(size_t)(g0 + j) * Ssp];
            #pragma unroll
            for (int j = 0; j < 16; j++) a += v[j];
        }
        s0 = a;
    }

    float m = s0;
    #pragma unroll
    for (int off = 32; off; off >>= 1) m = fmaxf(m, __shfl_xor(m, off));
    if (lane == 0) red[wv] = m;
    __syncthreads();
    m = red[0];
    #pragma unroll
    for (int w = 1; w < 6; w++) m = fmaxf(m, red[w]);
    __syncthreads();

    const float e0 = (tid < Ssp) ? __expf(s0 - m) : 0.f;
    float l = e0;
    #pragma unroll
    for (int off = 32; off; off >>= 1) l += __shfl_xor(l, off);
    if (lane == 0) red[wv] = l;
    __syncthreads();
    l = red[0] + red[1] + red[2] + red[3] + red[4] + red[5];

    if (tid < Ssp)
        wts[(size_t)b * Ssp + tid] = e0 / l;
}

// ---------------------------------------------------------------------------
// K4: weighted pooling, direct reads. grid (64, 32) = 2048 blocks = 8/CU
// (round-5 occupancy fix). Wave owns 16 channels, 4-row ILP, lane = s.
// Near the mixed HBM/L3 floor (~17 us).
// ---------------------------------------------------------------------------
__global__ __launch_bounds__(256) void k_pool(
    const float* __restrict__ img, const float* __restrict__ wts,
    float* __restrict__ out)
{
    const int b    = blockIdx.x;
    const int cg   = blockIdx.y;          // 32 groups x 64 channels
    const int tid  = threadIdx.x;
    const int lane = tid & 63;
    const int wv   = tid >> 6;

    __shared__ float wL[Ssp];
    for (int s = tid; s < Ssp; s += 256)
        wL[s] = wts[(size_t)b * Ssp + s];
    __syncthreads();

    // preload this lane's 6 weights once (s = lane + 64k), reused for all rows
    float wreg[6];
    #pragma unroll
    for (int k = 0; k < 6; k++) {
        const int s = lane + 64 * k;
        wreg[k] = (s < Ssp) ? wL[s] : 0.f;   // stride-1 lanes: conflict-free
    }

    const float* base = img + ((size_t)b * Cch + (size_t)cg * 64) * Ssp;
    const int c0 = wv * 16;                  // wave's 16 channels

    for (int i = 0; i < 16; i += 4) {
        const float* r0 = base + (size_t)(c0 + i + 0) * Ssp;
        const float* r1 = base + (size_t)(c0 + i + 1) * Ssp;
        const float* r2 = base + (size_t)(c0 + i + 2) * Ssp;
        const float* r3 = base + (size_t)(c0 + i + 3) * Ssp;

        float a0 = 0.f, a1 = 0.f, a2 = 0.f, a3 = 0.f;
        #pragma unroll
        for (int k = 0; k < 6; k++) {
            const int s = lane + 64 * k;
            const bool ok = (s < Ssp);
            const float v0 = ok ? r0[s] : 0.f;
            const float v1 = ok ? r1[s] : 0.f;
            const float v2 = ok ? r2[s] : 0.f;
            const float v3 = ok ? r3[s] : 0.f;
            a0 += v0 * wreg[k];
            a1 += v1 * wreg[k];
            a2 += v2 * wreg[k];
            a3 += v3 * wreg[k];
        }
        #pragma unroll
        for (int off = 32; off; off >>= 1) {
            a0 += __shfl_xor(a0, off);
            a1 += __shfl_xor(a1, off);
            a2 += __shfl_xor(a2, off);
            a3 += __shfl_xor(a3, off);
        }
        if (lane == 0) {
            float* o = out + (size_t)b * Cch + (size_t)cg * 64 + c0 + i;
            o[0] = a0; o[1] = a1; o[2] = a2; o[3] = a3;
        }
    }
}

// ---------------------------------------------------------------------------
extern "C" void kernel_launch(void* const* d_in, const int* in_sizes, int n_in,
                              void* d_out, int out_size, void* d_ws, size_t ws_size,
                              hipStream_t stream) {
    const float* text = (const float*)d_in[0];   // [64, 768]
    const float* img  = (const float*)d_in[1];   // [64, 2048, 19, 19]
    const float* W    = (const float*)d_in[2];   // [2048, 768]
    const float* bias = (const float*)d_in[3];   // [2048]
    float* out = (float*)d_out;                  // [64, 2048]

    // ws: (qT slot retained for layout stability) + sims_part + wts
    float* qT        = (float*)d_ws;
    float* sims_part = qT + (size_t)Cch * Bsz;
    float* wts       = sims_part + (size_t)Bsz * NCG * Ssp;
    (void)qT;

    k_sims <<<dim3(NCG, Bsz), 384, 0, stream>>>(text, W, bias, img, sims_part);
    k_wts  <<<dim3(Bsz),      384, 0, stream>>>(sims_part, wts);
    k_pool <<<dim3(Bsz, 32),  256, 0, stream>>>(img, wts, out);
}